// Round 4
// baseline (279.731 us; speedup 1.0000x reference)
//
#include <hip/hip_runtime.h>
#include <math.h>

#define HH   128
#define WW   128
#define HWP  16384      // H*W
#define CIN  64
#define COUT 128

// ws layout (floats): wt [576][128] at 0 (73728), ow4 [9*64*7] float4 at 73728
// total = 73728 + 16128 = 89856 floats = 351 KB  (stays tiny: round-1 failure
// was ws overflow clobbering an input buffer between graph replays)
#define WT_OFF   ((size_t)0)
#define OW4_OFF  ((size_t)73728)

// ---------------- prep: weight transposes ----------------
// wt[(kk*64+c)*128 + oc]   = weight[(oc*64+c)*9 + kk]           (main conv)
// ow4[(tap*64+c)*7 + g].i  = offset_w[((4g+i)*64+c)*9 + tap]    (offset conv)
__global__ __launch_bounds__(256) void k_prep_w(const float* __restrict__ wgt,
                                                const float* __restrict__ ow,
                                                float* __restrict__ wt,
                                                float4* __restrict__ ow4) {
    int tid = blockIdx.x * 256 + threadIdx.x;
    if (tid < 576 * 128) {
        int oc = tid & 127;
        int rest = tid >> 7;       // kk*64 + c
        int c = rest & 63;
        int kk = rest >> 6;
        wt[tid] = wgt[((size_t)oc * CIN + c) * 9 + kk];
    }
    if (tid < 9 * 64 * 7) {
        int g   = tid % 7;
        int c   = (tid / 7) & 63;
        int tap = tid / (7 * 64);
        float4 v = {0.f, 0.f, 0.f, 0.f};
        int oc = g * 4;
        if (oc + 0 < 27) v.x = ow[((size_t)(oc + 0) * CIN + c) * 9 + tap];
        if (oc + 1 < 27) v.y = ow[((size_t)(oc + 1) * CIN + c) * 9 + tap];
        if (oc + 2 < 27) v.z = ow[((size_t)(oc + 2) * CIN + c) * 9 + tap];
        if (oc + 3 < 27) v.w = ow[((size_t)(oc + 3) * CIN + c) * 9 + tap];
        ow4[tid] = v;
    }
}

// ---------------- fused: offset-conv + bilinear + implicit GEMM ----------------
// block = 32 pixels of one row (b, h, w0..w0+31) x all 128 oc; 256 threads
__global__ __launch_bounds__(256) void k_fused(const float* __restrict__ x,
                                               const float* __restrict__ wt,
                                               const float4* __restrict__ ow4,
                                               const float* __restrict__ ob,
                                               const float* __restrict__ bias,
                                               float* __restrict__ out) {
    __shared__ float  M[64 * 32];       // patch tile (stage A) / modulated tile (main)
    __shared__ float4 wbuf[448];        // offset-conv weight slice for one tap
    __shared__ float  meta_s[3 * 9 * 32]; // [comp][kk][p]: offy, offx, mask

    int blk = blockIdx.x;               // 2048
    int b   = blk >> 9;
    int rem = blk & 511;
    int h   = rem >> 2;
    int w0  = (rem & 3) << 5;
    int t   = threadIdx.x;

    int p1 = t & 31;                    // pixel in tile
    int cg = t >> 5;                    // 8-channel group (also oc4-group g in stage A)

    const float* xb = x + (size_t)b * CIN * HWP;

    // ================= stage A: 27-channel 3x3 offset conv =================
    float o0 = 0.f, o1 = 0.f, o2 = 0.f, o3 = 0.f;   // 4 oc accumulators (g = cg)
    for (int tap = 0; tap < 9; ++tap) {
        __syncthreads();                // prev tap's compute finished reading M
        int ky = tap / 3, kx = tap % 3;
        int yy = h - 1 + ky;
        int xx = w0 - 1 + kx + p1;
        bool vld = (yy >= 0) && (yy < HH) && (xx >= 0) && (xx < WW);
        int  sidx = (yy >= 0 ? yy : 0) * WW + (xx >= 0 ? (xx < WW ? xx : WW - 1) : 0);
        // stage patch[c][p] (zero-padded conv input)
#pragma unroll
        for (int i = 0; i < 8; ++i) {
            int c = cg * 8 + i;
            M[c * 32 + p1] = vld ? xb[(size_t)c * HWP + sidx] : 0.f;
        }
        // stage this tap's offset-conv weights (448 float4)
        wbuf[t] = ow4[(size_t)tap * 448 + t];
        if (t + 256 < 448) wbuf[t + 256] = ow4[(size_t)tap * 448 + t + 256];
        __syncthreads();
        if (cg < 7) {
#pragma unroll 8
            for (int c = 0; c < 64; ++c) {
                float  av = M[c * 32 + p1];       // lanes stride-1: conflict-free
                float4 w4 = wbuf[c * 7 + cg];     // half-wave uniform: broadcast
                o0 += av * w4.x; o1 += av * w4.y;
                o2 += av * w4.z; o3 += av * w4.w;
            }
        }
    }
    // postprocess -> meta_s (offy ch 2kk, offx ch 2kk+1, mask sigmoid ch 18+kk)
    if (cg < 7) {
        float oa[4] = {o0, o1, o2, o3};
#pragma unroll
        for (int j = 0; j < 4; ++j) {
            int oc = cg * 4 + j;
            if (oc < 27) {
                float v = oa[j] + ob[oc];
                if (oc < 18) {
                    meta_s[(oc & 1) * 288 + (oc >> 1) * 32 + p1] = v;
                } else {
                    meta_s[2 * 288 + (oc - 18) * 32 + p1] = 1.f / (1.f + expf(-v));
                }
            }
        }
    }
    __syncthreads();   // meta_s ready; M free for main loop

    // ================= main: bilinear sample + modulate + GEMM =================
    float acc[16];
#pragma unroll
    for (int i = 0; i < 16; ++i) acc[i] = 0.f;
    int pg  = t & 7,  ocg = t >> 3;
    int p0  = pg << 2, oc0 = ocg << 2;

    for (int kk = 0; kk < 9; ++kk) {
        // ---- phase 1: M[c][p] = mask * bilinear(x, c, py, px) ----
        {
            int ky = kk / 3, kx = kk % 3;
            float offy = meta_s[kk * 32 + p1];
            float offx = meta_s[288 + kk * 32 + p1];
            float msk  = meta_s[576 + kk * 32 + p1];
            float py = (float)(h - 1 + ky) + offy;
            float px = (float)(w0 + p1 - 1 + kx) + offx;
            float y0f = floorf(py), x0f = floorf(px);
            float ly = py - y0f, lx = px - x0f;
            int y0 = (int)y0f, x0i = (int)x0f;
            int y1 = y0 + 1, x1 = x0i + 1;
            bool vy0 = (y0 >= 0) && (y0 < HH);
            bool vy1 = (y1 >= 0) && (y1 < HH);
            bool vx0 = (x0i >= 0) && (x0i < WW);
            bool vx1 = (x1 >= 0) && (x1 < WW);
            int yc0 = min(max(y0, 0), HH - 1), yc1 = min(max(y1, 0), HH - 1);
            int xc0 = min(max(x0i, 0), WW - 1), xc1 = min(max(x1, 0), WW - 1);
            float w00 = (1.f - ly) * (1.f - lx) * ((vy0 && vx0) ? msk : 0.f);
            float w01 = (1.f - ly) * lx         * ((vy0 && vx1) ? msk : 0.f);
            float w10 = ly * (1.f - lx)         * ((vy1 && vx0) ? msk : 0.f);
            float w11 = ly * lx                 * ((vy1 && vx1) ? msk : 0.f);
            int idx00 = yc0 * WW + xc0, idx01 = yc0 * WW + xc1;
            int idx10 = yc1 * WW + xc0, idx11 = yc1 * WW + xc1;
            const float* basec = xb + (size_t)(cg * 8) * HWP;
#pragma unroll
            for (int i = 0; i < 8; ++i) {
                const float* bc = basec + (size_t)i * HWP;
                float s = w00 * bc[idx00] + w01 * bc[idx01]
                        + w10 * bc[idx10] + w11 * bc[idx11];
                M[(cg * 8 + i) * 32 + p1] = s;
            }
        }
        __syncthreads();

        // ---- phase 2: acc[oc0..+3][p0..+3] += wt[kk][c][oc] * M[c][p] ----
        const float* wrow = wt + (size_t)kk * 64 * 128;
#pragma unroll 4
        for (int k = 0; k < 64; ++k) {
            float4 wv = *(const float4*)(wrow + (size_t)k * 128 + oc0);
            float4 mv = *(const float4*)(&M[k * 32 + p0]);
            acc[0]  += wv.x * mv.x;  acc[1]  += wv.x * mv.y;
            acc[2]  += wv.x * mv.z;  acc[3]  += wv.x * mv.w;
            acc[4]  += wv.y * mv.x;  acc[5]  += wv.y * mv.y;
            acc[6]  += wv.y * mv.z;  acc[7]  += wv.y * mv.w;
            acc[8]  += wv.z * mv.x;  acc[9]  += wv.z * mv.y;
            acc[10] += wv.z * mv.z;  acc[11] += wv.z * mv.w;
            acc[12] += wv.w * mv.x;  acc[13] += wv.w * mv.y;
            acc[14] += wv.w * mv.z;  acc[15] += wv.w * mv.w;
        }
        __syncthreads();
    }

    // ---- epilogue: bias + coalesced float4 stores ----
    size_t obase = ((size_t)(b * COUT + oc0)) * HWP + (size_t)h * WW + w0 + p0;
#pragma unroll
    for (int i = 0; i < 4; ++i) {
        float bi = bias[oc0 + i];
        float4 v;
        v.x = acc[i * 4 + 0] + bi;
        v.y = acc[i * 4 + 1] + bi;
        v.z = acc[i * 4 + 2] + bi;
        v.w = acc[i * 4 + 3] + bi;
        *(float4*)(out + obase + (size_t)i * HWP) = v;
    }
}

extern "C" void kernel_launch(void* const* d_in, const int* in_sizes, int n_in,
                              void* d_out, int out_size, void* d_ws, size_t ws_size,
                              hipStream_t stream) {
    const float* x    = (const float*)d_in[0];
    const float* ow   = (const float*)d_in[1];
    const float* ob   = (const float*)d_in[2];
    const float* wgt  = (const float*)d_in[3];
    const float* bias = (const float*)d_in[4];
    float* out = (float*)d_out;
    float* ws  = (float*)d_ws;

    float*  wt  = ws + WT_OFF;
    float4* ow4 = (float4*)(ws + OW4_OFF);

    hipLaunchKernelGGL(k_prep_w, dim3(288), dim3(256), 0, stream, wgt, ow, wt, ow4);
    hipLaunchKernelGGL(k_fused, dim3(2048), dim3(256), 0, stream, x, wt, ow4, ob, bias, out);
}

// Round 5
// 172.777 us; speedup vs baseline: 1.6190x; 1.6190x over previous
//
#include <hip/hip_runtime.h>
#include <math.h>

#define HH   128
#define WW   128
#define HWP  16384      // H*W
#define CIN  64
#define COUT 128

typedef float  f32x4  __attribute__((ext_vector_type(4)));
typedef short  short8 __attribute__((ext_vector_type(8)));

// ws layout (floats): ow4 [9*64*7] float4 at 0 (16128 floats),
// wbf bf16 [128][576] at 16128 (73728 ushort = 36864 floats). total 212 KB.
#define OW4_OFF  ((size_t)0)
#define WBF_OFF  ((size_t)16128)

__device__ inline unsigned short f2bf(float f) {
    unsigned u = __builtin_bit_cast(unsigned, f);
    return (unsigned short)((u + 0x7FFFu + ((u >> 16) & 1u)) >> 16);   // RNE
}

// ---------------- prep: weight transposes ----------------
// wbf[oc*576 + kk*64 + c]  = bf16(weight[(oc*64+c)*9 + kk])   (main conv, MFMA A)
// ow4[(tap*64+c)*7 + g].i  = offset_w[((4g+i)*64+c)*9 + tap]  (offset conv)
__global__ __launch_bounds__(256) void k_prep_w(const float* __restrict__ wgt,
                                                const float* __restrict__ ow,
                                                unsigned short* __restrict__ wbf,
                                                float4* __restrict__ ow4) {
    int tid = blockIdx.x * 256 + threadIdx.x;   // 288*256 = 73728 exactly
    {
        int oc = tid / 576;
        int r  = tid - oc * 576;
        int kk = r >> 6;
        int c  = r & 63;
        wbf[tid] = f2bf(wgt[((size_t)oc * CIN + c) * 9 + kk]);
    }
    if (tid < 9 * 64 * 7) {
        int g   = tid % 7;
        int c   = (tid / 7) & 63;
        int tap = tid / (7 * 64);
        float4 v = {0.f, 0.f, 0.f, 0.f};
        int oc = g * 4;
        if (oc + 0 < 27) v.x = ow[((size_t)(oc + 0) * CIN + c) * 9 + tap];
        if (oc + 1 < 27) v.y = ow[((size_t)(oc + 1) * CIN + c) * 9 + tap];
        if (oc + 2 < 27) v.z = ow[((size_t)(oc + 2) * CIN + c) * 9 + tap];
        if (oc + 3 < 27) v.w = ow[((size_t)(oc + 3) * CIN + c) * 9 + tap];
        ow4[tid] = v;
    }
}

// ---------------- fused: offset-conv + bilinear + MFMA GEMM ----------------
// block = 32 pixels of one row (b, h, w0..w0+31) x all 128 oc; 256 threads
__global__ __launch_bounds__(256) void k_fused(const float* __restrict__ x,
                                               const unsigned short* __restrict__ wbf,
                                               const float4* __restrict__ ow4,
                                               const float* __restrict__ ob,
                                               const float* __restrict__ bias,
                                               float* __restrict__ out) {
    __shared__ float  Mraw[2048];         // stage A: fp32 [64c][32p]  (8 KB)
                                          // main:    2x bf16 [32p][64k] swizzled dbuf
    __shared__ float4 wbuf[448];          // offset-conv weight slice for one tap
    __shared__ float  meta_s[3 * 9 * 32]; // [comp][kk][p]: offy, offx, mask

    int blk = blockIdx.x;                 // 2048
    int b   = blk >> 9;
    int rem = blk & 511;
    int h   = rem >> 2;
    int w0  = (rem & 3) << 5;
    int t   = threadIdx.x;

    int p1 = t & 31;                      // pixel in tile
    int cg = t >> 5;                      // 8-channel group

    const float* xb = x + (size_t)b * CIN * HWP;

    // ================= stage A: 27-channel 3x3 offset conv (fp32 VALU) =========
    float o0 = 0.f, o1 = 0.f, o2 = 0.f, o3 = 0.f;
    for (int tap = 0; tap < 9; ++tap) {
        __syncthreads();
        int ky = tap / 3, kx = tap % 3;
        int yy = h - 1 + ky;
        int xx = w0 - 1 + kx + p1;
        bool vld = (yy >= 0) && (yy < HH) && (xx >= 0) && (xx < WW);
        int  sidx = (yy >= 0 ? yy : 0) * WW + (xx >= 0 ? (xx < WW ? xx : WW - 1) : 0);
#pragma unroll
        for (int i = 0; i < 8; ++i) {
            int c = cg * 8 + i;
            Mraw[c * 32 + p1] = vld ? xb[(size_t)c * HWP + sidx] : 0.f;
        }
        wbuf[t] = ow4[(size_t)tap * 448 + t];
        if (t + 256 < 448) wbuf[t + 256] = ow4[(size_t)tap * 448 + t + 256];
        __syncthreads();
        if (cg < 7) {
#pragma unroll 8
            for (int c = 0; c < 64; ++c) {
                float  av = Mraw[c * 32 + p1];     // stride-1: conflict-free
                float4 w4 = wbuf[c * 7 + cg];      // uniform: broadcast
                o0 += av * w4.x; o1 += av * w4.y;
                o2 += av * w4.z; o3 += av * w4.w;
            }
        }
    }
    if (cg < 7) {
        float oa[4] = {o0, o1, o2, o3};
#pragma unroll
        for (int j = 0; j < 4; ++j) {
            int oc = cg * 4 + j;
            if (oc < 27) {
                float v = oa[j] + ob[oc];
                if (oc < 18) {
                    meta_s[(oc & 1) * 288 + (oc >> 1) * 32 + p1] = v;
                } else {
                    meta_s[2 * 288 + (oc - 18) * 32 + p1] = 1.f / (1.f + expf(-v));
                }
            }
        }
    }
    __syncthreads();   // meta_s ready; Mraw free for main loop

    // ================= main: bilinear -> bf16 LDS tile -> MFMA =================
    int l   = t & 63;
    int wid = t >> 6;                    // wave 0..3 -> oc [wid*32, wid*32+32)
    int lm  = l & 15, lk = l >> 4;       // lk in 0..3

    f32x4 acc00 = {0.f,0.f,0.f,0.f};     // (ocf0, px 0-15)
    f32x4 acc01 = {0.f,0.f,0.f,0.f};     // (ocf0, px 16-31)
    f32x4 acc10 = {0.f,0.f,0.f,0.f};     // (ocf1, px 0-15)
    f32x4 acc11 = {0.f,0.f,0.f,0.f};     // (ocf1, px 16-31)

    // A-frag rows: lane l covers oc = base + (l&15), k = (l>>4)*8 + j
    const unsigned short* arow0 = wbf + (size_t)(wid * 32 + lm) * 576 + lk * 8;
    const unsigned short* arow1 = arow0 + 16 * 576;

    int pA = lm, pB = lm + 16;           // B-frag pixels (n = lane&15 per half)
    char* mbase = (char*)Mraw;
    int rbA = pA * 128, rbB = pB * 128;
    int swA = pA & 7,   swB = pB & 7;

    for (int kk = 0; kk < 9; ++kk) {
        // ---- phase 1: bilinear sample, pack bf16, swizzled LDS write ----
        {
            char* wdst = mbase + (kk & 1) * 4096;
            int ky = kk / 3, kx = kk % 3;
            float offy = meta_s[kk * 32 + p1];
            float offx = meta_s[288 + kk * 32 + p1];
            float msk  = meta_s[576 + kk * 32 + p1];
            float py = (float)(h - 1 + ky) + offy;
            float px = (float)(w0 + p1 - 1 + kx) + offx;
            float y0f = floorf(py), x0f = floorf(px);
            float ly = py - y0f, lx = px - x0f;
            int y0 = (int)y0f, x0i = (int)x0f;
            int y1 = y0 + 1, x1 = x0i + 1;
            bool vy0 = (y0 >= 0) && (y0 < HH);
            bool vy1 = (y1 >= 0) && (y1 < HH);
            bool vx0 = (x0i >= 0) && (x0i < WW);
            bool vx1 = (x1 >= 0) && (x1 < WW);
            int yc0 = min(max(y0, 0), HH - 1), yc1 = min(max(y1, 0), HH - 1);
            int xc0 = min(max(x0i, 0), WW - 1), xc1 = min(max(x1, 0), WW - 1);
            float w00 = (1.f - ly) * (1.f - lx) * ((vy0 && vx0) ? msk : 0.f);
            float w01 = (1.f - ly) * lx         * ((vy0 && vx1) ? msk : 0.f);
            float w10 = ly * (1.f - lx)         * ((vy1 && vx0) ? msk : 0.f);
            float w11 = ly * lx                 * ((vy1 && vx1) ? msk : 0.f);
            int idx00 = yc0 * WW + xc0, idx01 = yc0 * WW + xc1;
            int idx10 = yc1 * WW + xc0, idx11 = yc1 * WW + xc1;
            const float* basec = xb + (size_t)(cg * 8) * HWP;
            float s[8];
#pragma unroll
            for (int i = 0; i < 8; ++i) {
                const float* bc = basec + (size_t)i * HWP;
                s[i] = w00 * bc[idx00] + w01 * bc[idx01]
                     + w10 * bc[idx10] + w11 * bc[idx11];
            }
            uint4 pk;
            pk.x = (unsigned)f2bf(s[0]) | ((unsigned)f2bf(s[1]) << 16);
            pk.y = (unsigned)f2bf(s[2]) | ((unsigned)f2bf(s[3]) << 16);
            pk.z = (unsigned)f2bf(s[4]) | ((unsigned)f2bf(s[5]) << 16);
            pk.w = (unsigned)f2bf(s[6]) | ((unsigned)f2bf(s[7]) << 16);
            // M_bf[p1][k=cg*8..+7], col-block XOR-swizzled by (p1&7)
            *(uint4*)(wdst + p1 * 128 + (((unsigned)(cg ^ (p1 & 7))) << 4)) = pk;
        }
        __syncthreads();   // dbuf: single barrier per kk (write[n] vs read[n-1] safe)

        // ---- phase 2: 8 MFMAs over K=64 ----
        const char* rb = mbase + (kk & 1) * 4096;
#pragma unroll
        for (int sstep = 0; sstep < 2; ++sstep) {
            short8 a0 = *(const short8*)(arow0 + kk * 64 + sstep * 32);
            short8 a1 = *(const short8*)(arow1 + kk * 64 + sstep * 32);
            int kb = sstep * 4 + lk;
            short8 b0 = *(const short8*)(rb + rbA + ((kb ^ swA) << 4));
            short8 b1 = *(const short8*)(rb + rbB + ((kb ^ swB) << 4));
            acc00 = __builtin_amdgcn_mfma_f32_16x16x32_bf16(a0, b0, acc00, 0, 0, 0);
            acc01 = __builtin_amdgcn_mfma_f32_16x16x32_bf16(a0, b1, acc01, 0, 0, 0);
            acc10 = __builtin_amdgcn_mfma_f32_16x16x32_bf16(a1, b0, acc10, 0, 0, 0);
            acc11 = __builtin_amdgcn_mfma_f32_16x16x32_bf16(a1, b1, acc11, 0, 0, 0);
        }
    }

    // ---- epilogue: bias + stores (C map: col=lane&15 -> px, row=lk*4+r -> oc) ----
    size_t outb = (size_t)b * COUT * HWP + (size_t)h * WW + w0;
#pragma unroll
    for (int ocf = 0; ocf < 2; ++ocf) {
        f32x4 aP = ocf ? acc10 : acc00;
        f32x4 aQ = ocf ? acc11 : acc01;
        int ocb = wid * 32 + ocf * 16 + lk * 4;
#pragma unroll
        for (int r = 0; r < 4; ++r) {
            int oc = ocb + r;
            float bi = bias[oc];
            out[outb + (size_t)oc * HWP + pA] = aP[r] + bi;
            out[outb + (size_t)oc * HWP + pB] = aQ[r] + bi;
        }
    }
}

extern "C" void kernel_launch(void* const* d_in, const int* in_sizes, int n_in,
                              void* d_out, int out_size, void* d_ws, size_t ws_size,
                              hipStream_t stream) {
    const float* x    = (const float*)d_in[0];
    const float* ow   = (const float*)d_in[1];
    const float* ob   = (const float*)d_in[2];
    const float* wgt  = (const float*)d_in[3];
    const float* bias = (const float*)d_in[4];
    float* out = (float*)d_out;
    float* ws  = (float*)d_ws;

    float4*         ow4 = (float4*)(ws + OW4_OFF);
    unsigned short* wbf = (unsigned short*)(ws + WBF_OFF);

    hipLaunchKernelGGL(k_prep_w, dim3(288), dim3(256), 0, stream, wgt, ow, wbf, ow4);
    hipLaunchKernelGGL(k_fused, dim3(2048), dim3(256), 0, stream, x, wbf, ow4, ob, bias, out);
}

// Round 6
// 148.252 us; speedup vs baseline: 1.8869x; 1.1654x over previous
//
#include <hip/hip_runtime.h>
#include <math.h>

#define HH   128
#define WW   128
#define HWP  16384      // H*W
#define CIN  64
#define COUT 128

typedef float  f32x4  __attribute__((ext_vector_type(4)));
typedef short  short8 __attribute__((ext_vector_type(8)));

// ws layout (ushorts): wbf [128][576] at 0; owbf [32][576] at 73728. 180 KB.
#define WBF_OFF   ((size_t)0)
#define OWBF_OFF  ((size_t)73728)

__device__ inline unsigned short f2bf(float f) {
    unsigned u = __builtin_bit_cast(unsigned, f);
    return (unsigned short)((u + 0x7FFFu + ((u >> 16) & 1u)) >> 16);   // RNE
}

// ---------------- prep: bf16 weight transposes ----------------
// wbf [oc*576 + kk*64 + c]  = bf16(weight[(oc*64+c)*9 + kk])     (main conv A)
// owbf[oc*576 + tap*64 + c] = bf16(offset_w[(oc*64+c)*9 + tap])  (offset conv A, oc>=27 -> 0)
__global__ __launch_bounds__(256) void k_prep_w(const float* __restrict__ wgt,
                                                const float* __restrict__ ow,
                                                unsigned short* __restrict__ wbf,
                                                unsigned short* __restrict__ owbf) {
    int tid = blockIdx.x * 256 + threadIdx.x;   // 288*256 = 73728 exactly
    {
        int oc = tid / 576;
        int r  = tid - oc * 576;
        int kk = r >> 6;
        int c  = r & 63;
        wbf[tid] = f2bf(wgt[((size_t)oc * CIN + c) * 9 + kk]);
    }
    if (tid < 32 * 576) {
        int oc  = tid / 576;
        int r   = tid - oc * 576;
        int tap = r >> 6;
        int c   = r & 63;
        owbf[tid] = (oc < 27) ? f2bf(ow[((size_t)oc * CIN + c) * 9 + tap]) : 0;
    }
}

// ---------------- fused: MFMA offset-conv + bilinear + MFMA GEMM ----------------
// block = 32 pixels of one row (b, h, w0..w0+31) x all 128 oc; 256 threads
__global__ __launch_bounds__(256) void k_fused(const float* __restrict__ x,
                                               const unsigned short* __restrict__ wbf,
                                               const unsigned short* __restrict__ owbf,
                                               const float* __restrict__ ob,
                                               const float* __restrict__ bias,
                                               float* __restrict__ out) {
    __shared__ float  Mraw[2048];         // 2x bf16 [32p][64k] swizzled dbuf (8 KB)
    __shared__ float  meta_s[3 * 9 * 32]; // [comp][kk][p]: offy, offx, mask

    int blk = blockIdx.x;                 // 2048
    int b   = blk >> 9;
    int rem = blk & 511;
    int h   = rem >> 2;
    int w0  = (rem & 3) << 5;
    int t   = threadIdx.x;

    int p1 = t & 31;                      // pixel in tile (staging role)
    int cg = t >> 5;                      // 8-channel group (staging role)
    int l  = t & 63;
    int wid = t >> 6;                     // wave id
    int lm = l & 15, lk = l >> 4;

    const float* xb = x + (size_t)b * CIN * HWP;
    char* mbase = (char*)Mraw;

    // ================= stage A: offset conv via MFMA =================
    // wave quadrant: oc in [ocf*16,+16), px in [pxf*16,+16)
    int ocf = wid >> 1, pxf = wid & 1;
    int spx = pxf * 16 + lm;
    int srb = spx * 128, ssw = spx & 7;
    f32x4 sacc = {0.f, 0.f, 0.f, 0.f};
    const unsigned short* sab = owbf + (size_t)(ocf * 16 + lm) * 576 + lk * 8;

    for (int tap = 0; tap < 9; ++tap) {
        // stage integer-tap patch tile [32px][64c] bf16, swizzled, dbuf half tap&1
        {
            int ky = tap / 3, kx = tap % 3;
            int yy = h - 1 + ky;
            int xx = w0 - 1 + kx + p1;
            bool vld = (yy >= 0) && (yy < HH) && (xx >= 0) && (xx < WW);
            int  sidx = (yy >= 0 ? yy : 0) * WW + (xx >= 0 ? (xx < WW ? xx : WW - 1) : 0);
            float s[8];
#pragma unroll
            for (int i = 0; i < 8; ++i)
                s[i] = vld ? xb[(size_t)(cg * 8 + i) * HWP + sidx] : 0.f;
            uint4 pk;
            pk.x = (unsigned)f2bf(s[0]) | ((unsigned)f2bf(s[1]) << 16);
            pk.y = (unsigned)f2bf(s[2]) | ((unsigned)f2bf(s[3]) << 16);
            pk.z = (unsigned)f2bf(s[4]) | ((unsigned)f2bf(s[5]) << 16);
            pk.w = (unsigned)f2bf(s[6]) | ((unsigned)f2bf(s[7]) << 16);
            *(uint4*)(mbase + (tap & 1) * 4096 + p1 * 128 + (((unsigned)(cg ^ (p1 & 7))) << 4)) = pk;
        }
        __syncthreads();   // dbuf: single barrier per tap
        const char* prb = mbase + (tap & 1) * 4096;
#pragma unroll
        for (int ch = 0; ch < 2; ++ch) {
            short8 a  = *(const short8*)(sab + tap * 64 + ch * 32);
            int kb = ch * 4 + lk;
            short8 bf = *(const short8*)(prb + srb + ((kb ^ ssw) << 4));
            sacc = __builtin_amdgcn_mfma_f32_16x16x32_bf16(a, bf, sacc, 0, 0, 0);
        }
    }
    // postprocess own quadrant -> meta_s (C map: col=lane&15 -> px, row=lk*4+r -> oc)
#pragma unroll
    for (int r = 0; r < 4; ++r) {
        int oc = ocf * 16 + lk * 4 + r;
        if (oc < 27) {
            float v = sacc[r] + ob[oc];
            if (oc < 18) {
                meta_s[(oc & 1) * 288 + (oc >> 1) * 32 + spx] = v;
            } else {
                meta_s[2 * 288 + (oc - 18) * 32 + spx] = 1.f / (1.f + expf(-v));
            }
        }
    }
    __syncthreads();   // meta_s ready; stage-A tile reads drained

    // ================= main: bilinear -> bf16 LDS tile -> MFMA =================
    f32x4 acc00 = {0.f,0.f,0.f,0.f};     // (ocf0, px 0-15)
    f32x4 acc01 = {0.f,0.f,0.f,0.f};     // (ocf0, px 16-31)
    f32x4 acc10 = {0.f,0.f,0.f,0.f};     // (ocf1, px 0-15)
    f32x4 acc11 = {0.f,0.f,0.f,0.f};     // (ocf1, px 16-31)

    const unsigned short* arow0 = wbf + (size_t)(wid * 32 + lm) * 576 + lk * 8;
    const unsigned short* arow1 = arow0 + 16 * 576;

    int pA = lm, pB = lm + 16;
    int rbA = pA * 128, rbB = pB * 128;
    int swA = pA & 7,   swB = pB & 7;

    for (int kk = 0; kk < 9; ++kk) {
        // ---- phase 1: bilinear sample, pack bf16, swizzled LDS write ----
        {
            char* wdst = mbase + (kk & 1) * 4096;
            int ky = kk / 3, kx = kk % 3;
            float offy = meta_s[kk * 32 + p1];
            float offx = meta_s[288 + kk * 32 + p1];
            float msk  = meta_s[576 + kk * 32 + p1];
            float py = (float)(h - 1 + ky) + offy;
            float px = (float)(w0 + p1 - 1 + kx) + offx;
            float y0f = floorf(py), x0f = floorf(px);
            float ly = py - y0f, lx = px - x0f;
            int y0 = (int)y0f, x0i = (int)x0f;
            int y1 = y0 + 1, x1 = x0i + 1;
            bool vy0 = (y0 >= 0) && (y0 < HH);
            bool vy1 = (y1 >= 0) && (y1 < HH);
            bool vx0 = (x0i >= 0) && (x0i < WW);
            bool vx1 = (x1 >= 0) && (x1 < WW);
            int yc0 = min(max(y0, 0), HH - 1), yc1 = min(max(y1, 0), HH - 1);
            int xc0 = min(max(x0i, 0), WW - 1), xc1 = min(max(x1, 0), WW - 1);
            float w00 = (1.f - ly) * (1.f - lx) * ((vy0 && vx0) ? msk : 0.f);
            float w01 = (1.f - ly) * lx         * ((vy0 && vx1) ? msk : 0.f);
            float w10 = ly * (1.f - lx)         * ((vy1 && vx0) ? msk : 0.f);
            float w11 = ly * lx                 * ((vy1 && vx1) ? msk : 0.f);
            int idx00 = yc0 * WW + xc0, idx01 = yc0 * WW + xc1;
            int idx10 = yc1 * WW + xc0, idx11 = yc1 * WW + xc1;
            const float* basec = xb + (size_t)(cg * 8) * HWP;
            float s[8];
#pragma unroll
            for (int i = 0; i < 8; ++i) {
                const float* bc = basec + (size_t)i * HWP;
                s[i] = w00 * bc[idx00] + w01 * bc[idx01]
                     + w10 * bc[idx10] + w11 * bc[idx11];
            }
            uint4 pk;
            pk.x = (unsigned)f2bf(s[0]) | ((unsigned)f2bf(s[1]) << 16);
            pk.y = (unsigned)f2bf(s[2]) | ((unsigned)f2bf(s[3]) << 16);
            pk.z = (unsigned)f2bf(s[4]) | ((unsigned)f2bf(s[5]) << 16);
            pk.w = (unsigned)f2bf(s[6]) | ((unsigned)f2bf(s[7]) << 16);
            *(uint4*)(wdst + p1 * 128 + (((unsigned)(cg ^ (p1 & 7))) << 4)) = pk;
        }
        __syncthreads();   // dbuf: single barrier per kk

        // ---- phase 2: 8 MFMAs over K=64 ----
        const char* rb = mbase + (kk & 1) * 4096;
#pragma unroll
        for (int sstep = 0; sstep < 2; ++sstep) {
            short8 a0 = *(const short8*)(arow0 + kk * 64 + sstep * 32);
            short8 a1 = *(const short8*)(arow1 + kk * 64 + sstep * 32);
            int kb = sstep * 4 + lk;
            short8 b0 = *(const short8*)(rb + rbA + ((kb ^ swA) << 4));
            short8 b1 = *(const short8*)(rb + rbB + ((kb ^ swB) << 4));
            acc00 = __builtin_amdgcn_mfma_f32_16x16x32_bf16(a0, b0, acc00, 0, 0, 0);
            acc01 = __builtin_amdgcn_mfma_f32_16x16x32_bf16(a0, b1, acc01, 0, 0, 0);
            acc10 = __builtin_amdgcn_mfma_f32_16x16x32_bf16(a1, b0, acc10, 0, 0, 0);
            acc11 = __builtin_amdgcn_mfma_f32_16x16x32_bf16(a1, b1, acc11, 0, 0, 0);
        }
    }

    // ---- epilogue: bias + stores ----
    size_t outb = (size_t)b * COUT * HWP + (size_t)h * WW + w0;
#pragma unroll
    for (int of = 0; of < 2; ++of) {
        f32x4 aP = of ? acc10 : acc00;
        f32x4 aQ = of ? acc11 : acc01;
        int ocb = wid * 32 + of * 16 + lk * 4;
#pragma unroll
        for (int r = 0; r < 4; ++r) {
            int oc = ocb + r;
            float bi = bias[oc];
            out[outb + (size_t)oc * HWP + pA] = aP[r] + bi;
            out[outb + (size_t)oc * HWP + pB] = aQ[r] + bi;
        }
    }
}

extern "C" void kernel_launch(void* const* d_in, const int* in_sizes, int n_in,
                              void* d_out, int out_size, void* d_ws, size_t ws_size,
                              hipStream_t stream) {
    const float* x    = (const float*)d_in[0];
    const float* ow   = (const float*)d_in[1];
    const float* ob   = (const float*)d_in[2];
    const float* wgt  = (const float*)d_in[3];
    const float* bias = (const float*)d_in[4];
    float* out = (float*)d_out;
    unsigned short* wsu = (unsigned short*)d_ws;

    unsigned short* wbf  = wsu + WBF_OFF;
    unsigned short* owbf = wsu + OWBF_OFF;

    hipLaunchKernelGGL(k_prep_w, dim3(288), dim3(256), 0, stream, wgt, ow, wbf, owbf);
    hipLaunchKernelGGL(k_fused, dim3(2048), dim3(256), 0, stream, x, wbf, owbf, ob, bias, out);
}

// Round 7
// 146.921 us; speedup vs baseline: 1.9040x; 1.0091x over previous
//
#include <hip/hip_runtime.h>
#include <math.h>

#define HH   128
#define WW   128
#define HWP  16384      // H*W
#define CIN  64
#define COUT 128

typedef float  f32x4  __attribute__((ext_vector_type(4)));
typedef short  short8 __attribute__((ext_vector_type(8)));

// ws layout (ushorts): wbf [128][576] at 0; owbf [32][576] at 73728. 180 KB.
#define WBF_OFF   ((size_t)0)
#define OWBF_OFF  ((size_t)73728)

__device__ inline unsigned short f2bf(float f) {
    unsigned u = __builtin_bit_cast(unsigned, f);
    return (unsigned short)((u + 0x7FFFu + ((u >> 16) & 1u)) >> 16);   // RNE
}

// ---------------- prep: bf16 weight transposes ----------------
// wbf [oc*576 + kk*64 + c]  = bf16(weight[(oc*64+c)*9 + kk])     (main conv A)
// owbf[oc*576 + tap*64 + c] = bf16(offset_w[(oc*64+c)*9 + tap])  (offset conv A, oc>=27 -> 0)
__global__ __launch_bounds__(256) void k_prep_w(const float* __restrict__ wgt,
                                                const float* __restrict__ ow,
                                                unsigned short* __restrict__ wbf,
                                                unsigned short* __restrict__ owbf) {
    int tid = blockIdx.x * 256 + threadIdx.x;   // 288*256 = 73728 exactly
    {
        int oc = tid / 576;
        int r  = tid - oc * 576;
        int kk = r >> 6;
        int c  = r & 63;
        wbf[tid] = f2bf(wgt[((size_t)oc * CIN + c) * 9 + kk]);
    }
    if (tid < 32 * 576) {
        int oc  = tid / 576;
        int r   = tid - oc * 576;
        int tap = r >> 6;
        int c   = r & 63;
        owbf[tid] = (oc < 27) ? f2bf(ow[((size_t)oc * CIN + c) * 9 + tap]) : 0;
    }
}

// ---------------- fused: MFMA offset-conv + bilinear + MFMA GEMM ----------------
// block = 32 pixels of one row (b, h, w0..w0+31) x all 128 oc; 256 threads
// LDS: region [0,13312): stage-A context ctx[3][34][64] bf16 swizzled (13056 B),
//      ALIASED after a barrier by the main-loop 2x4KB bf16 dbuf;
//      region [13312,16768): meta_s[3][9][32] fp32.
__global__ __launch_bounds__(256) void k_fused(const float* __restrict__ x,
                                               const unsigned short* __restrict__ wbf,
                                               const unsigned short* __restrict__ owbf,
                                               const float* __restrict__ ob,
                                               const float* __restrict__ bias,
                                               float* __restrict__ out) {
    __shared__ __align__(16) char smem[16768];
    char*  ctx    = smem;                    // stage-A context (pre-alias)
    char*  mbase  = smem;                    // main-loop dbuf (post-alias)
    float* meta_s = (float*)(smem + 13312);  // [comp][kk][p]

    int blk = blockIdx.x;                 // 2048
    int b   = blk >> 9;
    int rem = blk & 511;
    int h   = rem >> 2;
    int w0  = (rem & 3) << 5;
    int t   = threadIdx.x;

    int p1 = t & 31;                      // pixel in tile (staging role)
    int cg = t >> 5;                      // 8-channel group (staging role)
    int l  = t & 63;
    int wid = t >> 6;                     // wave id
    int lm = l & 15, lk = l >> 4;

    const float* xb = x + (size_t)b * CIN * HWP;

    // ===== stage A part 1: stage 3x34x64 context ONCE (bf16, swizzled) =====
    // job j in [0,816): row=(j/34)>>3, cg=(j/34)&7, px=j%34 -> coalesced runs
#pragma unroll
    for (int c = 0; c < 4; ++c) {
        int j = c * 256 + t;
        if (j < 816) {
            int g   = j / 34;
            int px  = j - g * 34;         // 0..33
            int row = g >> 3;             // 0..2
            int cgj = g & 7;
            int yy = h - 1 + row;
            int xx = w0 - 1 + px;
            bool vld = (yy >= 0) && (yy < HH) && (xx >= 0) && (xx < WW);
            int  sidx = vld ? (yy * WW + xx) : 0;
            float s[8];
#pragma unroll
            for (int i = 0; i < 8; ++i)
                s[i] = vld ? xb[(size_t)(cgj * 8 + i) * HWP + sidx] : 0.f;
            uint4 pk;
            pk.x = (unsigned)f2bf(s[0]) | ((unsigned)f2bf(s[1]) << 16);
            pk.y = (unsigned)f2bf(s[2]) | ((unsigned)f2bf(s[3]) << 16);
            pk.z = (unsigned)f2bf(s[4]) | ((unsigned)f2bf(s[5]) << 16);
            pk.w = (unsigned)f2bf(s[6]) | ((unsigned)f2bf(s[7]) << 16);
            *(uint4*)(ctx + (row * 34 + px) * 128 + ((cgj ^ (px & 7)) << 4)) = pk;
        }
    }
    __syncthreads();

    // ===== stage A part 2: 9 taps x 2 MFMA, zero barriers (ctx read-only) =====
    int ocf = wid >> 1, pxf = wid & 1;    // wave quadrant: oc[ocf*16+), px[pxf*16+)
    int spx = pxf * 16 + lm;
    f32x4 sacc = {0.f, 0.f, 0.f, 0.f};
    const unsigned short* sab = owbf + (size_t)(ocf * 16 + lm) * 576 + lk * 8;

#pragma unroll
    for (int tap = 0; tap < 9; ++tap) {
        int ky = tap / 3, kx = tap % 3;
        int cpx = kx + spx;               // 0..33
        int crb = (ky * 34 + cpx) * 128;
        int csw = cpx & 7;
#pragma unroll
        for (int ch = 0; ch < 2; ++ch) {
            short8 a  = *(const short8*)(sab + tap * 64 + ch * 32);
            int kb = ch * 4 + lk;
            short8 bf = *(const short8*)(ctx + crb + (((unsigned)(kb ^ csw)) << 4));
            sacc = __builtin_amdgcn_mfma_f32_16x16x32_bf16(a, bf, sacc, 0, 0, 0);
        }
    }
    // postprocess own quadrant -> meta_s (C map: col=lane&15 -> px, row=lk*4+r -> oc)
#pragma unroll
    for (int r = 0; r < 4; ++r) {
        int oc = ocf * 16 + lk * 4 + r;
        if (oc < 27) {
            float v = sacc[r] + ob[oc];
            if (oc < 18) {
                meta_s[(oc & 1) * 288 + (oc >> 1) * 32 + spx] = v;
            } else {
                meta_s[2 * 288 + (oc - 18) * 32 + spx] = 1.f / (1.f + expf(-v));
            }
        }
    }
    __syncthreads();   // meta_s ready; all ctx reads drained -> mbase may alias

    // ================= main: bilinear -> bf16 LDS tile -> MFMA =================
    f32x4 acc00 = {0.f,0.f,0.f,0.f};     // (ocf0, px 0-15)
    f32x4 acc01 = {0.f,0.f,0.f,0.f};     // (ocf0, px 16-31)
    f32x4 acc10 = {0.f,0.f,0.f,0.f};     // (ocf1, px 0-15)
    f32x4 acc11 = {0.f,0.f,0.f,0.f};     // (ocf1, px 16-31)

    const unsigned short* arow0 = wbf + (size_t)(wid * 32 + lm) * 576 + lk * 8;
    const unsigned short* arow1 = arow0 + 16 * 576;

    int pA = lm, pB = lm + 16;
    int rbA = pA * 128, rbB = pB * 128;
    int swA = pA & 7,   swB = pB & 7;

    for (int kk = 0; kk < 9; ++kk) {
        // ---- phase 1: bilinear sample, pack bf16, swizzled LDS write ----
        {
            char* wdst = mbase + (kk & 1) * 4096;
            int ky = kk / 3, kx = kk % 3;
            float offy = meta_s[kk * 32 + p1];
            float offx = meta_s[288 + kk * 32 + p1];
            float msk  = meta_s[576 + kk * 32 + p1];
            float py = (float)(h - 1 + ky) + offy;
            float px = (float)(w0 + p1 - 1 + kx) + offx;
            float y0f = floorf(py), x0f = floorf(px);
            float ly = py - y0f, lx = px - x0f;
            int y0 = (int)y0f, x0i = (int)x0f;
            int y1 = y0 + 1, x1 = x0i + 1;
            bool vy0 = (y0 >= 0) && (y0 < HH);
            bool vy1 = (y1 >= 0) && (y1 < HH);
            bool vx0 = (x0i >= 0) && (x0i < WW);
            bool vx1 = (x1 >= 0) && (x1 < WW);
            int yc0 = min(max(y0, 0), HH - 1), yc1 = min(max(y1, 0), HH - 1);
            int xc0 = min(max(x0i, 0), WW - 1), xc1 = min(max(x1, 0), WW - 1);
            float w00 = (1.f - ly) * (1.f - lx) * ((vy0 && vx0) ? msk : 0.f);
            float w01 = (1.f - ly) * lx         * ((vy0 && vx1) ? msk : 0.f);
            float w10 = ly * (1.f - lx)         * ((vy1 && vx0) ? msk : 0.f);
            float w11 = ly * lx                 * ((vy1 && vx1) ? msk : 0.f);
            int idx00 = yc0 * WW + xc0, idx01 = yc0 * WW + xc1;
            int idx10 = yc1 * WW + xc0, idx11 = yc1 * WW + xc1;
            const float* basec = xb + (size_t)(cg * 8) * HWP;
            float s[8];
#pragma unroll
            for (int i = 0; i < 8; ++i) {
                const float* bc = basec + (size_t)i * HWP;
                s[i] = w00 * bc[idx00] + w01 * bc[idx01]
                     + w10 * bc[idx10] + w11 * bc[idx11];
            }
            uint4 pk;
            pk.x = (unsigned)f2bf(s[0]) | ((unsigned)f2bf(s[1]) << 16);
            pk.y = (unsigned)f2bf(s[2]) | ((unsigned)f2bf(s[3]) << 16);
            pk.z = (unsigned)f2bf(s[4]) | ((unsigned)f2bf(s[5]) << 16);
            pk.w = (unsigned)f2bf(s[6]) | ((unsigned)f2bf(s[7]) << 16);
            *(uint4*)(wdst + p1 * 128 + (((unsigned)(cg ^ (p1 & 7))) << 4)) = pk;
        }
        __syncthreads();   // dbuf: single barrier per kk

        // ---- phase 2: 8 MFMAs over K=64 ----
        const char* rb = mbase + (kk & 1) * 4096;
#pragma unroll
        for (int sstep = 0; sstep < 2; ++sstep) {
            short8 a0 = *(const short8*)(arow0 + kk * 64 + sstep * 32);
            short8 a1 = *(const short8*)(arow1 + kk * 64 + sstep * 32);
            int kb = sstep * 4 + lk;
            short8 b0 = *(const short8*)(rb + rbA + ((kb ^ swA) << 4));
            short8 b1 = *(const short8*)(rb + rbB + ((kb ^ swB) << 4));
            acc00 = __builtin_amdgcn_mfma_f32_16x16x32_bf16(a0, b0, acc00, 0, 0, 0);
            acc01 = __builtin_amdgcn_mfma_f32_16x16x32_bf16(a0, b1, acc01, 0, 0, 0);
            acc10 = __builtin_amdgcn_mfma_f32_16x16x32_bf16(a1, b0, acc10, 0, 0, 0);
            acc11 = __builtin_amdgcn_mfma_f32_16x16x32_bf16(a1, b1, acc11, 0, 0, 0);
        }
    }

    // ---- epilogue: bias + stores ----
    size_t outb = (size_t)b * COUT * HWP + (size_t)h * WW + w0;
#pragma unroll
    for (int of = 0; of < 2; ++of) {
        f32x4 aP = of ? acc10 : acc00;
        f32x4 aQ = of ? acc11 : acc01;
        int ocb = wid * 32 + of * 16 + lk * 4;
#pragma unroll
        for (int r = 0; r < 4; ++r) {
            int oc = ocb + r;
            float bi = bias[oc];
            out[outb + (size_t)oc * HWP + pA] = aP[r] + bi;
            out[outb + (size_t)oc * HWP + pB] = aQ[r] + bi;
        }
    }
}

extern "C" void kernel_launch(void* const* d_in, const int* in_sizes, int n_in,
                              void* d_out, int out_size, void* d_ws, size_t ws_size,
                              hipStream_t stream) {
    const float* x    = (const float*)d_in[0];
    const float* ow   = (const float*)d_in[1];
    const float* ob   = (const float*)d_in[2];
    const float* wgt  = (const float*)d_in[3];
    const float* bias = (const float*)d_in[4];
    float* out = (float*)d_out;
    unsigned short* wsu = (unsigned short*)d_ws;

    unsigned short* wbf  = wsu + WBF_OFF;
    unsigned short* owbf = wsu + OWBF_OFF;

    hipLaunchKernelGGL(k_prep_w, dim3(288), dim3(256), 0, stream, wgt, ow, wbf, owbf);
    hipLaunchKernelGGL(k_fused, dim3(2048), dim3(256), 0, stream, x, wbf, owbf, ob, bias, out);
}

// Round 8
// 142.019 us; speedup vs baseline: 1.9697x; 1.0345x over previous
//
#include <hip/hip_runtime.h>
#include <math.h>

#define HH   128
#define WW   128
#define HWP  16384      // H*W
#define CIN  64
#define COUT 128

typedef float  f32x4  __attribute__((ext_vector_type(4)));
typedef short  short8 __attribute__((ext_vector_type(8)));

// ws layout (ushorts): wbf [128][576] at 0; owbf [32][576] at 73728. 180 KB.
#define WBF_OFF   ((size_t)0)
#define OWBF_OFF  ((size_t)73728)

__device__ inline unsigned short f2bf(float f) {
    unsigned u = __builtin_bit_cast(unsigned, f);
    return (unsigned short)((u + 0x7FFFu + ((u >> 16) & 1u)) >> 16);   // RNE
}

// ---------------- prep: bf16 weight transposes ----------------
__global__ __launch_bounds__(256) void k_prep_w(const float* __restrict__ wgt,
                                                const float* __restrict__ ow,
                                                unsigned short* __restrict__ wbf,
                                                unsigned short* __restrict__ owbf) {
    int tid = blockIdx.x * 256 + threadIdx.x;   // 288*256 = 73728 exactly
    {
        int oc = tid / 576;
        int r  = tid - oc * 576;
        int kk = r >> 6;
        int c  = r & 63;
        wbf[tid] = f2bf(wgt[((size_t)oc * CIN + c) * 9 + kk]);
    }
    if (tid < 32 * 576) {
        int oc  = tid / 576;
        int r   = tid - oc * 576;
        int tap = r >> 6;
        int c   = r & 63;
        owbf[tid] = (oc < 27) ? f2bf(ow[((size_t)oc * CIN + c) * 9 + tap]) : 0;
    }
}

// ---------------- fused: MFMA offset-conv + pipelined bilinear + MFMA GEMM ----
// block = 32 pixels of one row x all 128 oc; 256 threads
__global__ __launch_bounds__(256) void k_fused(const float* __restrict__ x,
                                               const unsigned short* __restrict__ wbf,
                                               const unsigned short* __restrict__ owbf,
                                               const float* __restrict__ ob,
                                               const float* __restrict__ bias,
                                               float* __restrict__ out) {
    __shared__ __align__(16) char smem[16768];
    char*  ctx    = smem;                    // stage-A context (pre-alias)
    char*  mbase  = smem;                    // main-loop dbuf (post-alias)
    float* meta_s = (float*)(smem + 13312);  // [comp][kk][p]

    int blk = blockIdx.x;                 // 2048
    int b   = blk >> 9;
    int rem = blk & 511;
    int h   = rem >> 2;
    int w0  = (rem & 3) << 5;
    int t   = threadIdx.x;

    int p1 = t & 31;                      // pixel in tile (staging role)
    int cg = t >> 5;                      // 8-channel group (staging role)
    int l  = t & 63;
    int wid = t >> 6;                     // wave id
    int lm = l & 15, lk = l >> 4;

    const float* xb = x + (size_t)b * CIN * HWP;

    // ===== stage A part 1: stage 3x34x64 context ONCE (bf16, swizzled) =====
#pragma unroll
    for (int c = 0; c < 4; ++c) {
        int j = c * 256 + t;
        if (j < 816) {
            int g   = j / 34;
            int px  = j - g * 34;         // 0..33
            int row = g >> 3;             // 0..2
            int cgj = g & 7;
            int yy = h - 1 + row;
            int xx = w0 - 1 + px;
            bool vld = (yy >= 0) && (yy < HH) && (xx >= 0) && (xx < WW);
            int  sidx = vld ? (yy * WW + xx) : 0;
            float s[8];
#pragma unroll
            for (int i = 0; i < 8; ++i)
                s[i] = vld ? xb[(size_t)(cgj * 8 + i) * HWP + sidx] : 0.f;
            uint4 pk;
            pk.x = (unsigned)f2bf(s[0]) | ((unsigned)f2bf(s[1]) << 16);
            pk.y = (unsigned)f2bf(s[2]) | ((unsigned)f2bf(s[3]) << 16);
            pk.z = (unsigned)f2bf(s[4]) | ((unsigned)f2bf(s[5]) << 16);
            pk.w = (unsigned)f2bf(s[6]) | ((unsigned)f2bf(s[7]) << 16);
            *(uint4*)(ctx + (row * 34 + px) * 128 + ((cgj ^ (px & 7)) << 4)) = pk;
        }
    }
    __syncthreads();

    // ===== stage A part 2: 9 taps x 2 MFMA, zero barriers =====
    int ocf = wid >> 1, pxf = wid & 1;
    int spx = pxf * 16 + lm;
    f32x4 sacc = {0.f, 0.f, 0.f, 0.f};
    const unsigned short* sab = owbf + (size_t)(ocf * 16 + lm) * 576 + lk * 8;

#pragma unroll
    for (int tap = 0; tap < 9; ++tap) {
        int ky = tap / 3, kx = tap % 3;
        int cpx = kx + spx;
        int crb = (ky * 34 + cpx) * 128;
        int csw = cpx & 7;
#pragma unroll
        for (int ch = 0; ch < 2; ++ch) {
            short8 a  = *(const short8*)(sab + tap * 64 + ch * 32);
            int kb = ch * 4 + lk;
            short8 bf = *(const short8*)(ctx + crb + (((unsigned)(kb ^ csw)) << 4));
            sacc = __builtin_amdgcn_mfma_f32_16x16x32_bf16(a, bf, sacc, 0, 0, 0);
        }
    }
#pragma unroll
    for (int r = 0; r < 4; ++r) {
        int oc = ocf * 16 + lk * 4 + r;
        if (oc < 27) {
            float v = sacc[r] + ob[oc];
            if (oc < 18) {
                meta_s[(oc & 1) * 288 + (oc >> 1) * 32 + spx] = v;
            } else {
                meta_s[2 * 288 + (oc - 18) * 32 + spx] = 1.f / (1.f + expf(-v));
            }
        }
    }
    __syncthreads();   // meta_s ready; ctx reads drained -> mbase may alias

    // ================= main: software-pipelined bilinear -> MFMA =================
    f32x4 acc00 = {0.f,0.f,0.f,0.f};
    f32x4 acc01 = {0.f,0.f,0.f,0.f};
    f32x4 acc10 = {0.f,0.f,0.f,0.f};
    f32x4 acc11 = {0.f,0.f,0.f,0.f};

    const unsigned short* arow0 = wbf + (size_t)(wid * 32 + lm) * 576 + lk * 8;
    const unsigned short* arow1 = arow0 + 16 * 576;

    int pA = lm, pB = lm + 16;
    int rbA = pA * 128, rbB = pB * 128;
    int swA = pA & 7,   swB = pB & 7;

    // pipeline registers
    float  cw00, cw01, cw10, cw11;                 // corner weights (incl. mask)
    float  cc00[8], cc01[8], cc10[8], cc11[8];     // in-flight corner values
    short8 na0[2], na1[2];                         // in-flight A-frags

    // issue bilinear corner gathers for iteration KK (addresses from meta_s only)
#define PREF_CORNERS(KK) do {                                                  \
      int ky = (KK) / 3, kx = (KK) % 3;                                        \
      float offy = meta_s[(KK) * 32 + p1];                                     \
      float offx = meta_s[288 + (KK) * 32 + p1];                               \
      float msk  = meta_s[576 + (KK) * 32 + p1];                               \
      float py = (float)(h - 1 + ky) + offy;                                   \
      float px = (float)(w0 + p1 - 1 + kx) + offx;                             \
      float y0f = floorf(py), x0f = floorf(px);                                \
      float ly = py - y0f, lx = px - x0f;                                      \
      int y0 = (int)y0f, x0i = (int)x0f;                                       \
      int y1 = y0 + 1, x1 = x0i + 1;                                           \
      bool vy0 = (y0 >= 0) && (y0 < HH);                                       \
      bool vy1 = (y1 >= 0) && (y1 < HH);                                       \
      bool vx0 = (x0i >= 0) && (x0i < WW);                                     \
      bool vx1 = (x1 >= 0) && (x1 < WW);                                       \
      int yc0 = min(max(y0, 0), HH - 1), yc1 = min(max(y1, 0), HH - 1);        \
      int xc0 = min(max(x0i, 0), WW - 1), xc1 = min(max(x1, 0), WW - 1);       \
      cw00 = (1.f - ly) * (1.f - lx) * ((vy0 && vx0) ? msk : 0.f);             \
      cw01 = (1.f - ly) * lx         * ((vy0 && vx1) ? msk : 0.f);             \
      cw10 = ly * (1.f - lx)         * ((vy1 && vx0) ? msk : 0.f);             \
      cw11 = ly * lx                 * ((vy1 && vx1) ? msk : 0.f);             \
      int idx00 = yc0 * WW + xc0, idx01 = yc0 * WW + xc1;                      \
      int idx10 = yc1 * WW + xc0, idx11 = yc1 * WW + xc1;                      \
      const float* basec = xb + (size_t)(cg * 8) * HWP;                        \
      _Pragma("unroll")                                                        \
      for (int i = 0; i < 8; ++i) {                                            \
        const float* bc = basec + (size_t)i * HWP;                             \
        cc00[i] = bc[idx00]; cc01[i] = bc[idx01];                              \
        cc10[i] = bc[idx10]; cc11[i] = bc[idx11];                              \
      }                                                                        \
    } while (0)

#define PREF_AFRAG(KK) do {                                                    \
      na0[0] = *(const short8*)(arow0 + (KK) * 64);                            \
      na0[1] = *(const short8*)(arow0 + (KK) * 64 + 32);                       \
      na1[0] = *(const short8*)(arow1 + (KK) * 64);                            \
      na1[1] = *(const short8*)(arow1 + (KK) * 64 + 32);                       \
    } while (0)

    PREF_CORNERS(0);
    PREF_AFRAG(0);

#pragma unroll
    for (int kk = 0; kk < 9; ++kk) {
        // ---- combine + pack + swizzled LDS write (tile kk) ----
        {
            char* wdst = mbase + (kk & 1) * 4096;
            float s[8];
#pragma unroll
            for (int i = 0; i < 8; ++i)
                s[i] = cw00 * cc00[i] + cw01 * cc01[i]
                     + cw10 * cc10[i] + cw11 * cc11[i];
            uint4 pk;
            pk.x = (unsigned)f2bf(s[0]) | ((unsigned)f2bf(s[1]) << 16);
            pk.y = (unsigned)f2bf(s[2]) | ((unsigned)f2bf(s[3]) << 16);
            pk.z = (unsigned)f2bf(s[4]) | ((unsigned)f2bf(s[5]) << 16);
            pk.w = (unsigned)f2bf(s[6]) | ((unsigned)f2bf(s[7]) << 16);
            *(uint4*)(wdst + p1 * 128 + (((unsigned)(cg ^ (p1 & 7))) << 4)) = pk;
        }

        // ---- issue next tile's corner gathers BEFORE the barrier ----
        if (kk < 8) PREF_CORNERS(kk + 1);

        // ---- raw barrier: order LDS, leave global loads in flight ----
        asm volatile("s_waitcnt lgkmcnt(0)" ::: "memory");
        __builtin_amdgcn_s_barrier();
        __builtin_amdgcn_sched_barrier(0);

        // ---- MFMA (tile kk), A-frags prefetched last iteration ----
        const char* rb = mbase + (kk & 1) * 4096;
#pragma unroll
        for (int sstep = 0; sstep < 2; ++sstep) {
            short8 a0 = na0[sstep];
            short8 a1 = na1[sstep];
            int kb = sstep * 4 + lk;
            short8 b0 = *(const short8*)(rb + rbA + ((kb ^ swA) << 4));
            short8 b1 = *(const short8*)(rb + rbB + ((kb ^ swB) << 4));
            acc00 = __builtin_amdgcn_mfma_f32_16x16x32_bf16(a0, b0, acc00, 0, 0, 0);
            acc01 = __builtin_amdgcn_mfma_f32_16x16x32_bf16(a0, b1, acc01, 0, 0, 0);
            acc10 = __builtin_amdgcn_mfma_f32_16x16x32_bf16(a1, b0, acc10, 0, 0, 0);
            acc11 = __builtin_amdgcn_mfma_f32_16x16x32_bf16(a1, b1, acc11, 0, 0, 0);
        }

        // ---- issue next tile's A-frags (hidden under next combine+barrier) ----
        if (kk < 8) PREF_AFRAG(kk + 1);
    }

    // ---- epilogue: bias + stores ----
    size_t outb = (size_t)b * COUT * HWP + (size_t)h * WW + w0;
#pragma unroll
    for (int of = 0; of < 2; ++of) {
        f32x4 aP = of ? acc10 : acc00;
        f32x4 aQ = of ? acc11 : acc01;
        int ocb = wid * 32 + of * 16 + lk * 4;
#pragma unroll
        for (int r = 0; r < 4; ++r) {
            int oc = ocb + r;
            float bi = bias[oc];
            out[outb + (size_t)oc * HWP + pA] = aP[r] + bi;
            out[outb + (size_t)oc * HWP + pB] = aQ[r] + bi;
        }
    }
#undef PREF_CORNERS
#undef PREF_AFRAG
}

extern "C" void kernel_launch(void* const* d_in, const int* in_sizes, int n_in,
                              void* d_out, int out_size, void* d_ws, size_t ws_size,
                              hipStream_t stream) {
    const float* x    = (const float*)d_in[0];
    const float* ow   = (const float*)d_in[1];
    const float* ob   = (const float*)d_in[2];
    const float* wgt  = (const float*)d_in[3];
    const float* bias = (const float*)d_in[4];
    float* out = (float*)d_out;
    unsigned short* wsu = (unsigned short*)d_ws;

    unsigned short* wbf  = wsu + WBF_OFF;
    unsigned short* owbf = wsu + OWBF_OFF;

    hipLaunchKernelGGL(k_prep_w, dim3(288), dim3(256), 0, stream, wgt, ow, wbf, owbf);
    hipLaunchKernelGGL(k_fused, dim3(2048), dim3(256), 0, stream, x, wbf, owbf, ob, bias, out);
}

// Round 9
// 115.676 us; speedup vs baseline: 2.4182x; 1.2277x over previous
//
#include <hip/hip_runtime.h>
#include <math.h>

#define HH   128
#define WW   128
#define HWP  16384      // H*W
#define CIN  64
#define COUT 128

typedef float  f32x4  __attribute__((ext_vector_type(4)));
typedef short  short8 __attribute__((ext_vector_type(8)));

// ws layout (bytes): wbf [128][576] bf16 @0 (147456); owbf [32][576] bf16 @147456
// (73728); xt NHWC bf16 [4*16384][64] @221184 (8388608). NEED = 8609792.
#define WBF_B   ((size_t)0)
#define OWBF_B  ((size_t)147456)
#define XT_B    ((size_t)221184)
#define WS_NEED ((size_t)8609792)

__device__ inline unsigned short f2bf(float f) {
    unsigned u = __builtin_bit_cast(unsigned, f);
    return (unsigned short)((u + 0x7FFFu + ((u >> 16) & 1u)) >> 16);   // RNE
}

// ---------------- prep: bf16 weight transposes ----------------
__global__ __launch_bounds__(256) void k_prep_w(const float* __restrict__ wgt,
                                                const float* __restrict__ ow,
                                                unsigned short* __restrict__ wbf,
                                                unsigned short* __restrict__ owbf) {
    int tid = blockIdx.x * 256 + threadIdx.x;   // 288*256 = 73728 exactly
    {
        int oc = tid / 576;
        int r  = tid - oc * 576;
        int kk = r >> 6;
        int c  = r & 63;
        wbf[tid] = f2bf(wgt[((size_t)oc * CIN + c) * 9 + kk]);
    }
    if (tid < 32 * 576) {
        int oc  = tid / 576;
        int r   = tid - oc * 576;
        int tap = r >> 6;
        int c   = r & 63;
        owbf[tid] = (oc < 27) ? f2bf(ow[((size_t)oc * CIN + c) * 9 + tap]) : 0;
    }
}

// ---------------- prep: x NCHW fp32 -> NHWC bf16 ----------------
// thread (cgrp=t&7, px=t>>3): writes 16B contiguous; wave stores 1KB contiguous.
__global__ __launch_bounds__(256) void k_xt(const float* __restrict__ x,
                                            unsigned short* __restrict__ xt) {
    int t = threadIdx.x;
    int cgrp = t & 7, px = t >> 3;            // px 0..31
    int pix = blockIdx.x * 32 + px;           // grid 2048
    int b = pix >> 14, hw = pix & 16383;
    const float* xp = x + (size_t)b * CIN * HWP + (size_t)(cgrp * 8) * HWP + hw;
    unsigned pk[4];
#pragma unroll
    for (int d = 0; d < 4; ++d) {
        float lo = xp[(size_t)(2 * d) * HWP];
        float hi = xp[(size_t)(2 * d + 1) * HWP];
        pk[d] = (unsigned)f2bf(lo) | ((unsigned)f2bf(hi) << 16);
    }
    *(uint4*)(xt + (size_t)pix * 64 + cgrp * 8) = *(uint4*)pk;
}

// ================= v2: NHWC-bf16 fused kernel =================
// block = 32 pixels of one row x all 128 oc; 256 threads; LDS 11.6 KB
__global__ __launch_bounds__(256) void k_fused_v2(const unsigned short* __restrict__ xt,
                                                  const unsigned short* __restrict__ wbf,
                                                  const unsigned short* __restrict__ owbf,
                                                  const float* __restrict__ ob,
                                                  const float* __restrict__ bias,
                                                  float* __restrict__ out) {
    __shared__ __align__(16) char smem[11648];
    char*  mbase  = smem;                    // 2 x 4KB bf16 [32p][64k] swizzled dbuf
    float* meta_s = (float*)(smem + 8192);   // [comp][kk][p] 3456B

    int blk = blockIdx.x;                 // 2048
    int b   = blk >> 9;
    int rem = blk & 511;
    int h   = rem >> 2;
    int w0  = (rem & 3) << 5;
    int t   = threadIdx.x;

    int p1 = t & 31;                      // pixel in tile (staging role)
    int cg = t >> 5;                      // 8-channel group (staging role)
    int l  = t & 63;
    int wid = t >> 6;                     // wave id
    int lm = l & 15, lk = l >> 4;

    const unsigned short* xbt = xt + (size_t)b * HWP * 64;

    // ===== stage A: offset conv, B-frags DIRECT from global xt (no LDS) =====
    int ocf = wid >> 1, pxf = wid & 1;    // wave quadrant: oc[ocf*16+), px[pxf*16+)
    int spx = pxf * 16 + lm;
    f32x4 sacc = {0.f, 0.f, 0.f, 0.f};
    const unsigned short* sab = owbf + (size_t)(ocf * 16 + lm) * 576 + lk * 8;

#pragma unroll
    for (int tap = 0; tap < 9; ++tap) {
        int ky = tap / 3, kx = tap % 3;
        int yy = h - 1 + ky;
        int xx = w0 - 1 + kx + spx;
        bool vld = (yy >= 0) && (yy < HH) && (xx >= 0) && (xx < WW);
        int yc = min(max(yy, 0), HH - 1), xc = min(max(xx, 0), WW - 1);
        const unsigned short* bp = xbt + (size_t)(yc * WW + xc) * 64 + lk * 8;
#pragma unroll
        for (int ch = 0; ch < 2; ++ch) {
            short8 a = *(const short8*)(sab + tap * 64 + ch * 32);
            uint4 v = *(const uint4*)(bp + ch * 32);
            v.x = vld ? v.x : 0u;  v.y = vld ? v.y : 0u;
            v.z = vld ? v.z : 0u;  v.w = vld ? v.w : 0u;
            sacc = __builtin_amdgcn_mfma_f32_16x16x32_bf16(a, __builtin_bit_cast(short8, v), sacc, 0, 0, 0);
        }
    }
    // postprocess own quadrant -> meta_s (C map: col=lane&15 -> px, row=lk*4+r -> oc)
#pragma unroll
    for (int r = 0; r < 4; ++r) {
        int oc = ocf * 16 + lk * 4 + r;
        if (oc < 27) {
            float v = sacc[r] + ob[oc];
            if (oc < 18) {
                meta_s[(oc & 1) * 288 + (oc >> 1) * 32 + spx] = v;
            } else {
                meta_s[2 * 288 + (oc - 18) * 32 + spx] = 1.f / (1.f + expf(-v));
            }
        }
    }
    __syncthreads();   // meta_s ready

    // ================= main: pipelined bilinear (bf16x8 corners) -> MFMA =======
    f32x4 acc00 = {0.f,0.f,0.f,0.f};
    f32x4 acc01 = {0.f,0.f,0.f,0.f};
    f32x4 acc10 = {0.f,0.f,0.f,0.f};
    f32x4 acc11 = {0.f,0.f,0.f,0.f};

    const unsigned short* arow0 = wbf + (size_t)(wid * 32 + lm) * 576 + lk * 8;
    const unsigned short* arow1 = arow0 + 16 * 576;

    int pA = lm, pB = lm + 16;
    int rbA = pA * 128, rbB = pB * 128;
    int swA = pA & 7,   swB = pB & 7;

    // pipeline registers: 2-slot corner buffers (fully unrolled -> static idx)
    uint4 cc00[2], cc01[2], cc10[2], cc11[2];
    float cw00[2], cw01[2], cw10[2], cw11[2];
    short8 na0[2], na1[2];

    const unsigned short* xbc = xbt + cg * 8;   // this thread's channel slice

#define PREF_CORNERS(KK, BUF) do {                                             \
      int ky_ = (KK) / 3, kx_ = (KK) % 3;                                      \
      float offy = meta_s[(KK) * 32 + p1];                                     \
      float offx = meta_s[288 + (KK) * 32 + p1];                               \
      float msk  = meta_s[576 + (KK) * 32 + p1];                               \
      float py = (float)(h - 1 + ky_) + offy;                                  \
      float px = (float)(w0 + p1 - 1 + kx_) + offx;                            \
      float y0f = floorf(py), x0f = floorf(px);                                \
      float ly = py - y0f, lx = px - x0f;                                      \
      int y0 = (int)y0f, x0i = (int)x0f;                                       \
      int y1 = y0 + 1, x1 = x0i + 1;                                           \
      bool vy0 = (y0 >= 0) && (y0 < HH);                                       \
      bool vy1 = (y1 >= 0) && (y1 < HH);                                       \
      bool vx0 = (x0i >= 0) && (x0i < WW);                                     \
      bool vx1 = (x1 >= 0) && (x1 < WW);                                       \
      int yc0 = min(max(y0, 0), HH - 1), yc1 = min(max(y1, 0), HH - 1);        \
      int xc0 = min(max(x0i, 0), WW - 1), xc1 = min(max(x1, 0), WW - 1);       \
      cw00[BUF] = (1.f - ly) * (1.f - lx) * ((vy0 && vx0) ? msk : 0.f);        \
      cw01[BUF] = (1.f - ly) * lx         * ((vy0 && vx1) ? msk : 0.f);        \
      cw10[BUF] = ly * (1.f - lx)         * ((vy1 && vx0) ? msk : 0.f);        \
      cw11[BUF] = ly * lx                 * ((vy1 && vx1) ? msk : 0.f);        \
      cc00[BUF] = *(const uint4*)(xbc + (size_t)(yc0 * WW + xc0) * 64);        \
      cc01[BUF] = *(const uint4*)(xbc + (size_t)(yc0 * WW + xc1) * 64);        \
      cc10[BUF] = *(const uint4*)(xbc + (size_t)(yc1 * WW + xc0) * 64);        \
      cc11[BUF] = *(const uint4*)(xbc + (size_t)(yc1 * WW + xc1) * 64);        \
    } while (0)

#define PREF_AFRAG(KK) do {                                                    \
      na0[0] = *(const short8*)(arow0 + (KK) * 64);                            \
      na0[1] = *(const short8*)(arow0 + (KK) * 64 + 32);                       \
      na1[0] = *(const short8*)(arow1 + (KK) * 64);                            \
      na1[1] = *(const short8*)(arow1 + (KK) * 64 + 32);                       \
    } while (0)

    PREF_CORNERS(0, 0);
    PREF_AFRAG(0);

#pragma unroll
    for (int kk = 0; kk < 9; ++kk) {
        const int cur = kk & 1, nxt = (kk + 1) & 1;
        // ---- issue NEXT tile's corner loads first (deep overlap) ----
        if (kk < 8) PREF_CORNERS(kk + 1, nxt);

        // ---- combine (waits this tile's corners) + pack + swizzled LDS write --
        {
            char* wdst = mbase + cur * 4096;
            float w0c = cw00[cur], w1c = cw01[cur], w2c = cw10[cur], w3c = cw11[cur];
            unsigned pk[4];
#pragma unroll
            for (int d = 0; d < 4; ++d) {
                unsigned u0 = (&cc00[cur].x)[d], u1 = (&cc01[cur].x)[d];
                unsigned u2 = (&cc10[cur].x)[d], u3 = (&cc11[cur].x)[d];
                float lo = w0c * __builtin_bit_cast(float, u0 << 16)
                         + w1c * __builtin_bit_cast(float, u1 << 16)
                         + w2c * __builtin_bit_cast(float, u2 << 16)
                         + w3c * __builtin_bit_cast(float, u3 << 16);
                float hi = w0c * __builtin_bit_cast(float, u0 & 0xFFFF0000u)
                         + w1c * __builtin_bit_cast(float, u1 & 0xFFFF0000u)
                         + w2c * __builtin_bit_cast(float, u2 & 0xFFFF0000u)
                         + w3c * __builtin_bit_cast(float, u3 & 0xFFFF0000u);
                pk[d] = (unsigned)f2bf(lo) | ((unsigned)f2bf(hi) << 16);
            }
            *(uint4*)(wdst + p1 * 128 + (((unsigned)(cg ^ (p1 & 7))) << 4)) = *(uint4*)pk;
        }

        // ---- raw barrier: order LDS, leave global prefetches in flight ----
        asm volatile("s_waitcnt lgkmcnt(0)" ::: "memory");
        __builtin_amdgcn_s_barrier();
        __builtin_amdgcn_sched_barrier(0);

        // ---- MFMA (tile kk), A-frags prefetched last iteration ----
        const char* rb = mbase + cur * 4096;
#pragma unroll
        for (int sstep = 0; sstep < 2; ++sstep) {
            short8 a0 = na0[sstep];
            short8 a1 = na1[sstep];
            int kb = sstep * 4 + lk;
            short8 b0 = *(const short8*)(rb + rbA + ((kb ^ swA) << 4));
            short8 b1 = *(const short8*)(rb + rbB + ((kb ^ swB) << 4));
            acc00 = __builtin_amdgcn_mfma_f32_16x16x32_bf16(a0, b0, acc00, 0, 0, 0);
            acc01 = __builtin_amdgcn_mfma_f32_16x16x32_bf16(a0, b1, acc01, 0, 0, 0);
            acc10 = __builtin_amdgcn_mfma_f32_16x16x32_bf16(a1, b0, acc10, 0, 0, 0);
            acc11 = __builtin_amdgcn_mfma_f32_16x16x32_bf16(a1, b1, acc11, 0, 0, 0);
        }
        if (kk < 8) PREF_AFRAG(kk + 1);
    }
#undef PREF_CORNERS
#undef PREF_AFRAG

    // ---- epilogue: bias + stores ----
    size_t outb = (size_t)b * COUT * HWP + (size_t)h * WW + w0;
#pragma unroll
    for (int of = 0; of < 2; ++of) {
        f32x4 aP = of ? acc10 : acc00;
        f32x4 aQ = of ? acc11 : acc01;
        int ocb = wid * 32 + of * 16 + lk * 4;
#pragma unroll
        for (int r = 0; r < 4; ++r) {
            int oc = ocb + r;
            float bi = bias[oc];
            out[outb + (size_t)oc * HWP + pA] = aP[r] + bi;
            out[outb + (size_t)oc * HWP + pB] = aQ[r] + bi;
        }
    }
}

// ================= v1 fallback (R8 kernel, validated) =================
__global__ __launch_bounds__(256) void k_fused_v1(const float* __restrict__ x,
                                                  const unsigned short* __restrict__ wbf,
                                                  const unsigned short* __restrict__ owbf,
                                                  const float* __restrict__ ob,
                                                  const float* __restrict__ bias,
                                                  float* __restrict__ out) {
    __shared__ __align__(16) char smem[16768];
    char*  ctx    = smem;
    char*  mbase  = smem;
    float* meta_s = (float*)(smem + 13312);

    int blk = blockIdx.x;
    int b   = blk >> 9;
    int rem = blk & 511;
    int h   = rem >> 2;
    int w0  = (rem & 3) << 5;
    int t   = threadIdx.x;

    int p1 = t & 31;
    int cg = t >> 5;
    int l  = t & 63;
    int wid = t >> 6;
    int lm = l & 15, lk = l >> 4;

    const float* xb = x + (size_t)b * CIN * HWP;

#pragma unroll
    for (int c = 0; c < 4; ++c) {
        int j = c * 256 + t;
        if (j < 816) {
            int g   = j / 34;
            int px  = j - g * 34;
            int row = g >> 3;
            int cgj = g & 7;
            int yy = h - 1 + row;
            int xx = w0 - 1 + px;
            bool vld = (yy >= 0) && (yy < HH) && (xx >= 0) && (xx < WW);
            int  sidx = vld ? (yy * WW + xx) : 0;
            float s[8];
#pragma unroll
            for (int i = 0; i < 8; ++i)
                s[i] = vld ? xb[(size_t)(cgj * 8 + i) * HWP + sidx] : 0.f;
            uint4 pk;
            pk.x = (unsigned)f2bf(s[0]) | ((unsigned)f2bf(s[1]) << 16);
            pk.y = (unsigned)f2bf(s[2]) | ((unsigned)f2bf(s[3]) << 16);
            pk.z = (unsigned)f2bf(s[4]) | ((unsigned)f2bf(s[5]) << 16);
            pk.w = (unsigned)f2bf(s[6]) | ((unsigned)f2bf(s[7]) << 16);
            *(uint4*)(ctx + (row * 34 + px) * 128 + ((cgj ^ (px & 7)) << 4)) = pk;
        }
    }
    __syncthreads();

    int ocf = wid >> 1, pxf = wid & 1;
    int spx = pxf * 16 + lm;
    f32x4 sacc = {0.f, 0.f, 0.f, 0.f};
    const unsigned short* sab = owbf + (size_t)(ocf * 16 + lm) * 576 + lk * 8;

#pragma unroll
    for (int tap = 0; tap < 9; ++tap) {
        int ky = tap / 3, kx = tap % 3;
        int cpx = kx + spx;
        int crb = (ky * 34 + cpx) * 128;
        int csw = cpx & 7;
#pragma unroll
        for (int ch = 0; ch < 2; ++ch) {
            short8 a  = *(const short8*)(sab + tap * 64 + ch * 32);
            int kb = ch * 4 + lk;
            short8 bf = *(const short8*)(ctx + crb + (((unsigned)(kb ^ csw)) << 4));
            sacc = __builtin_amdgcn_mfma_f32_16x16x32_bf16(a, bf, sacc, 0, 0, 0);
        }
    }
#pragma unroll
    for (int r = 0; r < 4; ++r) {
        int oc = ocf * 16 + lk * 4 + r;
        if (oc < 27) {
            float v = sacc[r] + ob[oc];
            if (oc < 18) {
                meta_s[(oc & 1) * 288 + (oc >> 1) * 32 + spx] = v;
            } else {
                meta_s[2 * 288 + (oc - 18) * 32 + spx] = 1.f / (1.f + expf(-v));
            }
        }
    }
    __syncthreads();

    f32x4 acc00 = {0.f,0.f,0.f,0.f};
    f32x4 acc01 = {0.f,0.f,0.f,0.f};
    f32x4 acc10 = {0.f,0.f,0.f,0.f};
    f32x4 acc11 = {0.f,0.f,0.f,0.f};

    const unsigned short* arow0 = wbf + (size_t)(wid * 32 + lm) * 576 + lk * 8;
    const unsigned short* arow1 = arow0 + 16 * 576;

    int pA = lm, pB = lm + 16;
    int rbA = pA * 128, rbB = pB * 128;
    int swA = pA & 7,   swB = pB & 7;

    float  cw00, cw01, cw10, cw11;
    float  cc00[8], cc01[8], cc10[8], cc11[8];
    short8 na0[2], na1[2];

#define PREF_CORNERS(KK) do {                                                  \
      int ky = (KK) / 3, kx = (KK) % 3;                                        \
      float offy = meta_s[(KK) * 32 + p1];                                     \
      float offx = meta_s[288 + (KK) * 32 + p1];                               \
      float msk  = meta_s[576 + (KK) * 32 + p1];                               \
      float py = (float)(h - 1 + ky) + offy;                                   \
      float px = (float)(w0 + p1 - 1 + kx) + offx;                             \
      float y0f = floorf(py), x0f = floorf(px);                                \
      float ly = py - y0f, lx = px - x0f;                                      \
      int y0 = (int)y0f, x0i = (int)x0f;                                       \
      int y1 = y0 + 1, x1 = x0i + 1;                                           \
      bool vy0 = (y0 >= 0) && (y0 < HH);                                       \
      bool vy1 = (y1 >= 0) && (y1 < HH);                                       \
      bool vx0 = (x0i >= 0) && (x0i < WW);                                     \
      bool vx1 = (x1 >= 0) && (x1 < WW);                                       \
      int yc0 = min(max(y0, 0), HH - 1), yc1 = min(max(y1, 0), HH - 1);        \
      int xc0 = min(max(x0i, 0), WW - 1), xc1 = min(max(x1, 0), WW - 1);       \
      cw00 = (1.f - ly) * (1.f - lx) * ((vy0 && vx0) ? msk : 0.f);             \
      cw01 = (1.f - ly) * lx         * ((vy0 && vx1) ? msk : 0.f);             \
      cw10 = ly * (1.f - lx)         * ((vy1 && vx0) ? msk : 0.f);             \
      cw11 = ly * lx                 * ((vy1 && vx1) ? msk : 0.f);             \
      int idx00 = yc0 * WW + xc0, idx01 = yc0 * WW + xc1;                      \
      int idx10 = yc1 * WW + xc0, idx11 = yc1 * WW + xc1;                      \
      const float* basec = xb + (size_t)(cg * 8) * HWP;                        \
      _Pragma("unroll")                                                        \
      for (int i = 0; i < 8; ++i) {                                            \
        const float* bc = basec + (size_t)i * HWP;                             \
        cc00[i] = bc[idx00]; cc01[i] = bc[idx01];                              \
        cc10[i] = bc[idx10]; cc11[i] = bc[idx11];                              \
      }                                                                        \
    } while (0)

#define PREF_AFRAG(KK) do {                                                    \
      na0[0] = *(const short8*)(arow0 + (KK) * 64);                            \
      na0[1] = *(const short8*)(arow0 + (KK) * 64 + 32);                       \
      na1[0] = *(const short8*)(arow1 + (KK) * 64);                            \
      na1[1] = *(const short8*)(arow1 + (KK) * 64 + 32);                       \
    } while (0)

    PREF_CORNERS(0);
    PREF_AFRAG(0);

#pragma unroll
    for (int kk = 0; kk < 9; ++kk) {
        {
            char* wdst = mbase + (kk & 1) * 4096;
            float s[8];
#pragma unroll
            for (int i = 0; i < 8; ++i)
                s[i] = cw00 * cc00[i] + cw01 * cc01[i]
                     + cw10 * cc10[i] + cw11 * cc11[i];
            uint4 pk;
            pk.x = (unsigned)f2bf(s[0]) | ((unsigned)f2bf(s[1]) << 16);
            pk.y = (unsigned)f2bf(s[2]) | ((unsigned)f2bf(s[3]) << 16);
            pk.z = (unsigned)f2bf(s[4]) | ((unsigned)f2bf(s[5]) << 16);
            pk.w = (unsigned)f2bf(s[6]) | ((unsigned)f2bf(s[7]) << 16);
            *(uint4*)(wdst + p1 * 128 + (((unsigned)(cg ^ (p1 & 7))) << 4)) = pk;
        }
        if (kk < 8) PREF_CORNERS(kk + 1);
        asm volatile("s_waitcnt lgkmcnt(0)" ::: "memory");
        __builtin_amdgcn_s_barrier();
        __builtin_amdgcn_sched_barrier(0);
        const char* rb = mbase + (kk & 1) * 4096;
#pragma unroll
        for (int sstep = 0; sstep < 2; ++sstep) {
            short8 a0 = na0[sstep];
            short8 a1 = na1[sstep];
            int kb = sstep * 4 + lk;
            short8 b0 = *(const short8*)(rb + rbA + ((kb ^ swA) << 4));
            short8 b1 = *(const short8*)(rb + rbB + ((kb ^ swB) << 4));
            acc00 = __builtin_amdgcn_mfma_f32_16x16x32_bf16(a0, b0, acc00, 0, 0, 0);
            acc01 = __builtin_amdgcn_mfma_f32_16x16x32_bf16(a0, b1, acc01, 0, 0, 0);
            acc10 = __builtin_amdgcn_mfma_f32_16x16x32_bf16(a1, b0, acc10, 0, 0, 0);
            acc11 = __builtin_amdgcn_mfma_f32_16x16x32_bf16(a1, b1, acc11, 0, 0, 0);
        }
        if (kk < 8) PREF_AFRAG(kk + 1);
    }
#undef PREF_CORNERS
#undef PREF_AFRAG

    size_t outb = (size_t)b * COUT * HWP + (size_t)h * WW + w0;
#pragma unroll
    for (int of = 0; of < 2; ++of) {
        f32x4 aP = of ? acc10 : acc00;
        f32x4 aQ = of ? acc11 : acc01;
        int ocb = wid * 32 + of * 16 + lk * 4;
#pragma unroll
        for (int r = 0; r < 4; ++r) {
            int oc = ocb + r;
            float bi = bias[oc];
            out[outb + (size_t)oc * HWP + pA] = aP[r] + bi;
            out[outb + (size_t)oc * HWP + pB] = aQ[r] + bi;
        }
    }
}

extern "C" void kernel_launch(void* const* d_in, const int* in_sizes, int n_in,
                              void* d_out, int out_size, void* d_ws, size_t ws_size,
                              hipStream_t stream) {
    const float* x    = (const float*)d_in[0];
    const float* ow   = (const float*)d_in[1];
    const float* ob   = (const float*)d_in[2];
    const float* wgt  = (const float*)d_in[3];
    const float* bias = (const float*)d_in[4];
    float* out = (float*)d_out;
    char* ws = (char*)d_ws;

    unsigned short* wbf  = (unsigned short*)(ws + WBF_B);
    unsigned short* owbf = (unsigned short*)(ws + OWBF_B);
    unsigned short* xt   = (unsigned short*)(ws + XT_B);

    hipLaunchKernelGGL(k_prep_w, dim3(288), dim3(256), 0, stream, wgt, ow, wbf, owbf);
    if (ws_size >= WS_NEED) {
        hipLaunchKernelGGL(k_xt, dim3(2048), dim3(256), 0, stream, x, xt);
        hipLaunchKernelGGL(k_fused_v2, dim3(2048), dim3(256), 0, stream,
                           xt, wbf, owbf, ob, bias, out);
    } else {
        hipLaunchKernelGGL(k_fused_v1, dim3(2048), dim3(256), 0, stream,
                           x, wbf, owbf, ob, bias, out);
    }
}